// Round 11
// baseline (152.190 us; speedup 1.0000x reference)
//
#include <hip/hip_runtime.h>
#include <hip/hip_bf16.h>
#include <hip/hip_fp16.h>

#define DIM 64
#define HEADS 4
#define HD 256   // HEADS*DIM
#define CAP 64   // padded CSR capacity per node

typedef __attribute__((ext_vector_type(8))) short bf16x8;
typedef __attribute__((ext_vector_type(8))) unsigned short u16x8;
typedef __attribute__((ext_vector_type(4))) float f32x4;

// ---------------------------------------------------------------------------
// helpers
// ---------------------------------------------------------------------------
template<int CTRL>
__device__ __forceinline__ float dpp_rot(float x) {
    return __int_as_float(__builtin_amdgcn_update_dpp(
        0, __float_as_int(x), CTRL, 0xF, 0xF, true));
}
// sum across each 16-lane row via rotational Hillis-Steele (pure VALU DPP)
__device__ __forceinline__ float reduce16(float x) {
    x += dpp_rot<0x121>(x);   // row_ror:1
    x += dpp_rot<0x122>(x);   // row_ror:2
    x += dpp_rot<0x124>(x);   // row_ror:4
    x += dpp_rot<0x128>(x);   // row_ror:8
    return x;
}
__device__ __forceinline__ unsigned short f2bf(float f) {
    unsigned u = __float_as_uint(f);
    unsigned r = (u + 0x7FFFu + ((u >> 16) & 1u)) >> 16;   // RNE
    return (unsigned short)r;
}
__device__ __forceinline__ float bf2f(unsigned short u) {
    return __uint_as_float((unsigned)u << 16);
}
// fp16 weight from packed CSR record
__device__ __forceinline__ float rec_w(unsigned rec) {
    return __half2float(__ushort_as_half((unsigned short)(rec & 0xffffu)));
}

// ---------------------------------------------------------------------------
// K1: CSR build into padded 4B slots: rec = (src<<16) | fp16(weight).
// counts pre-zeroed by memset.  One atomic + one 4B store per edge.
// ---------------------------------------------------------------------------
__global__ void scatter_all(const int* __restrict__ edges, const float* __restrict__ ew,
                            int* counts, unsigned* __restrict__ csr, int nE) {
    int e = blockIdx.x * blockDim.x + threadIdx.x;
    if (e < nE) {
        int dst = edges[nE + e];           // edges[1][e]
        int src = edges[e];
        float w = ew[e];
        int p = atomicAdd(&counts[dst], 1);
        unsigned rec = ((unsigned)src << 16)
                     | (unsigned)__half_as_ushort(__float2half(w));
        csr[(dst << 6) + p] = rec;
    }
}

// ---------------------------------------------------------------------------
// Shared f32 GEMM tile helpers (XOR-swizzled transposed A store).
// ---------------------------------------------------------------------------
__device__ __forceinline__ void tile_load_A(float (*As)[68], const float* __restrict__ A,
                                            int row0, int n, int tid) {
    int c4 = (tid & 15) * 4;
    int sw = (tid & 7) << 2;
    #pragma unroll
    for (int it = 0; it < 4; ++it) {
        int r = (tid >> 4) + it * 16;
        float4 val = make_float4(0.f, 0.f, 0.f, 0.f);
        if (row0 + r < n)
            val = *reinterpret_cast<const float4*>(A + (size_t)(row0 + r) * DIM + c4);
        int rs = r ^ sw;
        As[c4 + 0][rs] = val.x;
        As[c4 + 1][rs] = val.y;
        As[c4 + 2][rs] = val.z;
        As[c4 + 3][rs] = val.w;
    }
}

__device__ __forceinline__ void tile_mm(const float (*As)[68], const float (*Bs)[68],
                                        float acc[4][4], int r0, int c0) {
    #pragma unroll 8
    for (int kk = 0; kk < 64; ++kk) {
        int sw = ((kk >> 2) & 7) << 2;
        float4 av = *reinterpret_cast<const float4*>(&As[kk][r0 ^ sw]);
        float4 bv = *reinterpret_cast<const float4*>(&Bs[kk][c0]);
        float a_[4] = {av.x, av.y, av.z, av.w};
        float b_[4] = {bv.x, bv.y, bv.z, bv.w};
        #pragma unroll
        for (int i = 0; i < 4; ++i)
            #pragma unroll
            for (int j = 0; j < 4; ++j)
                acc[i][j] += a_[i] * b_[j];
    }
}

// ---------------------------------------------------------------------------
// K2: xws = dinv[row] * (f_mole @ gcn_w) in bf16.  deg/dinv computed in-kernel
// from the padded CSR (threads 0..63, one row each, result staged in LDS).
// ---------------------------------------------------------------------------
__global__ __launch_bounds__(256) void gemm_xw(const float* __restrict__ A,
                                               const float* __restrict__ W,
                                               const int* __restrict__ counts,
                                               const unsigned* __restrict__ csr,
                                               float* __restrict__ dinv,
                                               unsigned short* __restrict__ out,
                                               int n) {
    __shared__ float As[64][68];
    __shared__ float Bs[64][68];
    __shared__ float dloc[64];
    int row0 = blockIdx.x * 64;
    int tid = threadIdx.x;

    if (tid < 64) {
        int r = row0 + tid;
        if (r < n) {
            int c = counts[r];
            const unsigned* p = csr + ((size_t)r << 6);
            float s = 0.f;
            for (int j = 0; j < c; ++j) s += rec_w(p[j]);
            float d = rsqrtf(s + 1.0f);    // +1 = self-loop weight
            dinv[r] = d;
            dloc[tid] = d;
        }
    }

    tile_load_A(As, A, row0, n, tid);
    #pragma unroll
    for (int it = 0; it < 4; ++it) {
        int r  = (tid >> 4) + it * 16;
        int c4 = (tid & 15) * 4;
        *reinterpret_cast<float4*>(&Bs[r][c4]) =
            *reinterpret_cast<const float4*>(W + (size_t)r * DIM + c4);
    }
    __syncthreads();
    int r0 = (tid >> 4) * 4;
    int c0 = (tid & 15) * 4;
    float acc[4][4] = {};
    tile_mm(As, Bs, acc, r0, c0);
    #pragma unroll
    for (int i = 0; i < 4; ++i) {
        int r = row0 + r0 + i;
        if (r >= n) continue;
        float d = dloc[r0 + i];
        ushort4 u;
        u.x = f2bf(d * acc[i][0]); u.y = f2bf(d * acc[i][1]);
        u.z = f2bf(d * acc[i][2]); u.w = f2bf(d * acc[i][3]);
        *reinterpret_cast<ushort4*>(out + (size_t)r * DIM + c0) = u;
    }
}

// ---------------------------------------------------------------------------
// K3: GCN aggregation.  4B CSR records; output f_gcn bf16.
// ---------------------------------------------------------------------------
__global__ __launch_bounds__(256) void gcn_agg(const unsigned short* __restrict__ xws,
                                               const int* __restrict__ counts,
                                               const unsigned* __restrict__ csr,
                                               const float* __restrict__ dinv,
                                               const float* __restrict__ gcn_b,
                                               unsigned short* __restrict__ f_gcnh, int n) {
    int wave = threadIdx.x >> 6;
    int lane = threadIdx.x & 63;
    int i = blockIdx.x * 4 + wave;
    if (i >= n) return;
    int eo = lane >> 4;
    int cg = lane & 15;

    float4 acc = make_float4(0.f, 0.f, 0.f, 0.f);
    int e0 = i << 6;
    int e1 = e0 + counts[i];
    int eb = e0;
    for (; eb + 16 <= e1; eb += 16) {
        unsigned p[4];
        #pragma unroll
        for (int j = 0; j < 4; ++j) p[j] = csr[eb + 4 * j + eo];
        ushort4 x[4];
        #pragma unroll
        for (int j = 0; j < 4; ++j)
            x[j] = *reinterpret_cast<const ushort4*>(xws + (size_t)(p[j] >> 16) * DIM + cg * 4);
        #pragma unroll
        for (int j = 0; j < 4; ++j) {
            float c = rec_w(p[j]);
            acc.x += c * bf2f(x[j].x); acc.y += c * bf2f(x[j].y);
            acc.z += c * bf2f(x[j].z); acc.w += c * bf2f(x[j].w);
        }
    }
    for (int e = eb + eo; e < e1; e += 4) {
        unsigned p = csr[e];
        float c = rec_w(p);
        ushort4 x4 = *reinterpret_cast<const ushort4*>(xws + (size_t)(p >> 16) * DIM + cg * 4);
        acc.x += c * bf2f(x4.x); acc.y += c * bf2f(x4.y);
        acc.z += c * bf2f(x4.z); acc.w += c * bf2f(x4.w);
    }
    acc.x += __shfl_xor(acc.x, 16, 64); acc.x += __shfl_xor(acc.x, 32, 64);
    acc.y += __shfl_xor(acc.y, 16, 64); acc.y += __shfl_xor(acc.y, 32, 64);
    acc.z += __shfl_xor(acc.z, 16, 64); acc.z += __shfl_xor(acc.z, 32, 64);
    acc.w += __shfl_xor(acc.w, 16, 64); acc.w += __shfl_xor(acc.w, 32, 64);

    float di = dinv[i];
    ushort4 xs = *reinterpret_cast<const ushort4*>(xws + (size_t)i * DIM + cg * 4);
    const float* b = gcn_b + cg * 4;
    if (eo == 0) {
        ushort4 u;
        u.x = f2bf(fmaxf(di * (acc.x + bf2f(xs.x)) + b[0], 0.f));
        u.y = f2bf(fmaxf(di * (acc.y + bf2f(xs.y)) + b[1], 0.f));
        u.z = f2bf(fmaxf(di * (acc.z + bf2f(xs.z)) + b[2], 0.f));
        u.w = f2bf(fmaxf(di * (acc.w + bf2f(xs.w)) + b[3], 0.f));
        *reinterpret_cast<ushort4*>(f_gcnh + (size_t)i * DIM + cg * 4) = u;
    }
}

// ---------------------------------------------------------------------------
// K4: q/k/v/skip projections via MFMA, single block per 64-row tile.
// A fragments loaded ONCE into registers; loop over all 13 weight panels
// (0..3 q -> bf16 x0.125, 4..7 k, 8..11 v -> interleaved kv, 12 skip -> f32).
// Same wave writes k and v for its rows: no cross-XCD kv line sharing.
// ---------------------------------------------------------------------------
__global__ __launch_bounds__(256) void qkv_mfma(const unsigned short* __restrict__ Ah,
        const float* __restrict__ wq, const float* __restrict__ bq,
        const float* __restrict__ wk, const float* __restrict__ bk,
        const float* __restrict__ wv, const float* __restrict__ bv,
        const float* __restrict__ wsk, const float* __restrict__ bsk,
        unsigned short* __restrict__ qo, unsigned short* __restrict__ kvb,
        float* __restrict__ xrb, int n) {
    int row0 = blockIdx.x * 64;
    int wid  = threadIdx.x >> 6;
    int lane = threadIdx.x & 63;
    int hm = wid >> 1, hn = wid & 1;
    int lrow = lane & 15;
    int lk8  = (lane >> 4) * 8;

    // A fragments: 16B bf16 loads, once for all panels
    bf16x8 afr[2][2];   // [ks][fm]
    #pragma unroll
    for (int ks = 0; ks < 2; ++ks)
        #pragma unroll
        for (int fm = 0; fm < 2; ++fm) {
            int r = row0 + hm * 32 + fm * 16 + lrow;
            bf16x8 v8;
            if (r < n) {
                v8 = *reinterpret_cast<const bf16x8*>(Ah + (size_t)r * DIM + ks * 32 + lk8);
            } else {
                #pragma unroll
                for (int j = 0; j < 8; ++j) v8[j] = 0;
            }
            afr[ks][fm] = v8;
        }

    int drow = (lane >> 4) * 4;
    int dcol = lane & 15;

    #pragma unroll 1
    for (int ty = 0; ty < 13; ++ty) {
        const float* W; const float* bias; float scale = 1.0f;
        int ncw, mode;                  // 0=q, 1=k, 2=v, 3=skip
        int col0 = (ty & 3) * 64;
        if (ty < 4)       { W = wq;  bias = bq;  ncw = HD;  mode = 0; scale = 0.125f; }
        else if (ty < 8)  { W = wk;  bias = bk;  ncw = HD;  mode = 1; }
        else if (ty < 12) { W = wv;  bias = bv;  ncw = HD;  mode = 2; }
        else              { W = wsk; bias = bsk; ncw = DIM; mode = 3; col0 = 0; }

        // B fragments: strided f32 -> bf16
        bf16x8 bfr[2][2];   // [ks][fn]
        #pragma unroll
        for (int ks = 0; ks < 2; ++ks)
            #pragma unroll
            for (int fn = 0; fn < 2; ++fn) {
                int c = col0 + hn * 32 + fn * 16 + lrow;
                const float* wp = W + (size_t)(ks * 32 + lk8) * ncw + c;
                bf16x8 v8;
                #pragma unroll
                for (int j = 0; j < 8; ++j)
                    v8[j] = (short)f2bf(wp[(size_t)j * ncw]);
                bfr[ks][fn] = v8;
            }

        f32x4 zz = {0.f, 0.f, 0.f, 0.f};
        f32x4 acc[2][2] = {{zz, zz}, {zz, zz}};
        #pragma unroll
        for (int ks = 0; ks < 2; ++ks)
            #pragma unroll
            for (int fm = 0; fm < 2; ++fm)
                #pragma unroll
                for (int fn = 0; fn < 2; ++fn)
                    acc[fm][fn] = __builtin_amdgcn_mfma_f32_16x16x32_bf16(
                        afr[ks][fm], bfr[ks][fn], acc[fm][fn], 0, 0, 0);

        #pragma unroll
        for (int fm = 0; fm < 2; ++fm)
            #pragma unroll
            for (int fn = 0; fn < 2; ++fn) {
                int col = col0 + hn * 32 + fn * 16 + dcol;
                float bcol = bias[col];
                #pragma unroll
                for (int r = 0; r < 4; ++r) {
                    int row = row0 + hm * 32 + fm * 16 + drow + r;
                    if (row >= n) continue;
                    float val = (acc[fm][fn][r] + bcol) * scale;
                    if (mode == 0) {
                        qo[(size_t)row * HD + col] = f2bf(val);
                    } else if (mode == 3) {
                        xrb[(size_t)row * DIM + col] = val;
                    } else {
                        int h = col >> 6, c6 = col & 63;
                        kvb[(size_t)row * 512 + h * 128 + (c6 >> 2) * 8 + (c6 & 3)
                            + (mode == 2 ? 4 : 0)] = f2bf(val);
                    }
                }
            }
    }
}

// ---------------------------------------------------------------------------
// K5: fused attention + beta gate.  One wave per node.
// lane = (head = lane>>4, 4-chan group = lane&15).  kv interleaved bf16
// (one dwordx4 gather per edge per lane); q bf16, pre-scaled by 0.125.
// 8-edge unroll.  Logits small -> no max-tracking.
// ---------------------------------------------------------------------------
__global__ __launch_bounds__(256) void attn_fused(const unsigned short* __restrict__ q,
                                                  const unsigned short* __restrict__ kvb,
                                                  const float* __restrict__ x_r,
                                                  const int* __restrict__ counts,
                                                  const unsigned* __restrict__ csr,
                                                  const float* __restrict__ wbeta,
                                                  float* __restrict__ f_tf, int n) {
    int wave = threadIdx.x >> 6;
    int lane = threadIdx.x & 63;
    int i = blockIdx.x * 4 + wave;
    if (i >= n) return;
    int h  = lane >> 4;
    int cg = lane & 15;
    int kvoff = h * 128 + cg * 8;

    ushort4 qv = *reinterpret_cast<const ushort4*>(q + (size_t)i * HD + h * DIM + cg * 4);
    float4 q4;
    q4.x = bf2f(qv.x); q4.y = bf2f(qv.y); q4.z = bf2f(qv.z); q4.w = bf2f(qv.w);
    float z = 0.f;
    float4 a = make_float4(0.f, 0.f, 0.f, 0.f);

    int e0 = i << 6;
    int cnt = counts[i];
    int e1 = e0 + cnt;
    int e = e0;
    for (; e + 8 <= e1; e += 8) {
        int s[8];
        #pragma unroll
        for (int j = 0; j < 8; ++j) s[j] = (int)(csr[e + j] >> 16);
        u16x8 kv[8];
        #pragma unroll
        for (int j = 0; j < 8; ++j)
            kv[j] = *reinterpret_cast<const u16x8*>(kvb + (size_t)s[j] * 512 + kvoff);
        float pl[8];
        #pragma unroll
        for (int j = 0; j < 8; ++j)
            pl[j] = q4.x * bf2f(kv[j][0]) + q4.y * bf2f(kv[j][1])
                  + q4.z * bf2f(kv[j][2]) + q4.w * bf2f(kv[j][3]);
        #pragma unroll
        for (int j = 0; j < 8; ++j) pl[j] = reduce16(pl[j]);
        #pragma unroll
        for (int j = 0; j < 8; ++j) {
            float ez = __expf(pl[j]);
            z += ez;
            a.x += ez * bf2f(kv[j][4]); a.y += ez * bf2f(kv[j][5]);
            a.z += ez * bf2f(kv[j][6]); a.w += ez * bf2f(kv[j][7]);
        }
    }
    for (; e + 4 <= e1; e += 4) {
        int s[4];
        #pragma unroll
        for (int j = 0; j < 4; ++j) s[j] = (int)(csr[e + j] >> 16);
        u16x8 kv[4];
        #pragma unroll
        for (int j = 0; j < 4; ++j)
            kv[j] = *reinterpret_cast<const u16x8*>(kvb + (size_t)s[j] * 512 + kvoff);
        #pragma unroll
        for (int j = 0; j < 4; ++j) {
            float p = q4.x * bf2f(kv[j][0]) + q4.y * bf2f(kv[j][1])
                    + q4.z * bf2f(kv[j][2]) + q4.w * bf2f(kv[j][3]);
            p = reduce16(p);
            float ez = __expf(p);
            z += ez;
            a.x += ez * bf2f(kv[j][4]); a.y += ez * bf2f(kv[j][5]);
            a.z += ez * bf2f(kv[j][6]); a.w += ez * bf2f(kv[j][7]);
        }
    }
    for (; e < e1; ++e) {
        int s = (int)(csr[e] >> 16);
        u16x8 kv = *reinterpret_cast<const u16x8*>(kvb + (size_t)s * 512 + kvoff);
        float p = q4.x * bf2f(kv[0]) + q4.y * bf2f(kv[1])
                + q4.z * bf2f(kv[2]) + q4.w * bf2f(kv[3]);
        p = reduce16(p);
        float ez = __expf(p);
        z += ez;
        a.x += ez * bf2f(kv[4]); a.y += ez * bf2f(kv[5]);
        a.z += ez * bf2f(kv[6]); a.w += ez * bf2f(kv[7]);
    }

    float inv = (cnt > 0) ? 1.0f / z : 0.f;
    float4 o;
    o.x = a.x * inv; o.y = a.y * inv; o.z = a.z * inv; o.w = a.w * inv;
    o.x += __shfl_xor(o.x, 16, 64); o.x += __shfl_xor(o.x, 32, 64);
    o.y += __shfl_xor(o.y, 16, 64); o.y += __shfl_xor(o.y, 32, 64);
    o.z += __shfl_xor(o.z, 16, 64); o.z += __shfl_xor(o.z, 32, 64);
    o.w += __shfl_xor(o.w, 16, 64); o.w += __shfl_xor(o.w, 32, 64);
    o.x *= 0.25f; o.y *= 0.25f; o.z *= 0.25f; o.w *= 0.25f;

    float4 xr4 = *reinterpret_cast<const float4*>(x_r + (size_t)i * DIM + cg * 4);
    const float* w1 = wbeta + cg * 4;
    const float* w2 = wbeta + 64 + cg * 4;
    const float* w3 = wbeta + 128 + cg * 4;
    float t = o.x * w1[0] + o.y * w1[1] + o.z * w1[2] + o.w * w1[3]
            + xr4.x * w2[0] + xr4.y * w2[1] + xr4.z * w2[2] + xr4.w * w2[3]
            + (o.x - xr4.x) * w3[0] + (o.y - xr4.y) * w3[1]
            + (o.z - xr4.z) * w3[2] + (o.w - xr4.w) * w3[3];
    t = reduce16(t);
    float beta = 1.0f / (1.0f + __expf(-t));
    float4 r;
    r.x = fmaxf(beta * xr4.x + (1.0f - beta) * o.x, 0.f);
    r.y = fmaxf(beta * xr4.y + (1.0f - beta) * o.y, 0.f);
    r.z = fmaxf(beta * xr4.z + (1.0f - beta) * o.z, 0.f);
    r.w = fmaxf(beta * xr4.w + (1.0f - beta) * o.w, 0.f);
    if (h == 0)
        *reinterpret_cast<float4*>(f_tf + (size_t)i * DIM + cg * 4) = r;
}

// ---------------------------------------------------------------------------
// K6: conv projection, LDS-staged read-once tile.
// block = 64 nodes; stage f_tf tile (64x64, padded) in LDS; thread (o-group,
// node) computes 16 outputs; stores coalesced along n.
// ---------------------------------------------------------------------------
__global__ __launch_bounds__(256) void conv_out_k(const float* __restrict__ f_tf,
                                                  const float* __restrict__ conv_w,
                                                  const float* __restrict__ conv_b,
                                                  float* __restrict__ out, int n) {
    __shared__ float ft[64][65];
    int n0 = blockIdx.x * 64;
    int tid = threadIdx.x;
    int nd = tid >> 2, c16 = (tid & 3) * 16;
    if (n0 + nd < n) {
        #pragma unroll
        for (int j = 0; j < 4; ++j) {
            float4 v = *reinterpret_cast<const float4*>(
                f_tf + (size_t)(n0 + nd) * DIM + c16 + j * 4);
            ft[nd][c16 + j * 4 + 0] = v.x;
            ft[nd][c16 + j * 4 + 1] = v.y;
            ft[nd][c16 + j * 4 + 2] = v.z;
            ft[nd][c16 + j * 4 + 3] = v.w;
        }
    }
    __syncthreads();
    int nl = tid & 63;
    int og = tid >> 6;                // 0..3
    int nn = n0 + nl;
    if (nn >= n) return;
    #pragma unroll 1
    for (int oo = 0; oo < 16; ++oo) {
        int o = og * 16 + oo;
        const float* wr = conv_w + (size_t)o * DIM;
        float acc = conv_b[o];
        #pragma unroll
        for (int k = 0; k < 64; ++k) acc += ft[nl][k] * wr[k];
        out[(size_t)o * n + nn] = acc;
    }
}

// ---------------------------------------------------------------------------
// launch
// ---------------------------------------------------------------------------
extern "C" void kernel_launch(void* const* d_in, const int* in_sizes, int n_in,
                              void* d_out, int out_size, void* d_ws, size_t ws_size,
                              hipStream_t stream) {
    const float* f_mole = (const float*)d_in[0];
    const float* edge_w = (const float*)d_in[1];
    const float* gcn_w  = (const float*)d_in[2];
    const float* gcn_b  = (const float*)d_in[3];
    const float* wq     = (const float*)d_in[4];
    const float* bq     = (const float*)d_in[5];
    const float* wk     = (const float*)d_in[6];
    const float* bk     = (const float*)d_in[7];
    const float* wv     = (const float*)d_in[8];
    const float* bv     = (const float*)d_in[9];
    const float* wskip  = (const float*)d_in[10];
    const float* bskip  = (const float*)d_in[11];
    const float* wbeta  = (const float*)d_in[12];
    const float* conv_w = (const float*)d_in[13];
    const float* conv_b = (const float*)d_in[14];
    const int*   edges  = (const int*)d_in[15];

    int N = in_sizes[0] / DIM;
    int E = in_sizes[1];

    float* ws = (float*)d_ws;
    size_t o = 0;
    int*      counts = (int*)(ws + o);      o += N;      // must stay first (memset)
    float*    dinv   = ws + o;              o += N;
    unsigned* csr    = (unsigned*)(ws + o); o += (size_t)N * CAP;
    unsigned short* xws    = (unsigned short*)(ws + o); o += (size_t)N * DIM / 2;
    unsigned short* f_gcnh = (unsigned short*)(ws + o); o += (size_t)N * DIM / 2;
    unsigned short* qb     = (unsigned short*)(ws + o); o += (size_t)N * HD / 2;
    unsigned short* kvb    = (unsigned short*)(ws + o); o += (size_t)N * 512 / 2;
    float* xrb = ws + o;                    o += (size_t)N * DIM;
    float* ftf = ws + o;                    o += (size_t)N * DIM;

    int ebl = (E + 255) / 256;
    int gbl = (N + 63) / 64;

    hipMemsetAsync(d_ws, 0, (size_t)N * sizeof(int), stream);
    scatter_all<<<ebl, 256, 0, stream>>>(edges, edge_w, counts, csr, E);

    gemm_xw<<<gbl, 256, 0, stream>>>(f_mole, gcn_w, counts, csr, dinv, xws, N);
    gcn_agg<<<(N + 3) / 4, 256, 0, stream>>>(xws, counts, csr, dinv, gcn_b, f_gcnh, N);

    qkv_mfma<<<gbl, 256, 0, stream>>>(f_gcnh, wq, bq, wk, bk, wv, bv,
                                      wskip, bskip, qb, kvb, xrb, N);

    attn_fused<<<(N + 3) / 4, 256, 0, stream>>>(qb, kvb, xrb, counts, csr, wbeta, ftf, N);
    conv_out_k<<<gbl, 256, 0, stream>>>(ftf, conv_w, conv_b, (float*)d_out, N);
}

// Round 12
// 137.920 us; speedup vs baseline: 1.1035x; 1.1035x over previous
//
#include <hip/hip_runtime.h>
#include <hip/hip_bf16.h>
#include <hip/hip_fp16.h>

#define DIM 64
#define HEADS 4
#define HD 256   // HEADS*DIM
#define CAP 64   // padded CSR capacity per node

typedef __attribute__((ext_vector_type(8))) short bf16x8;
typedef __attribute__((ext_vector_type(8))) unsigned short u16x8;
typedef __attribute__((ext_vector_type(4))) float f32x4;

// ---------------------------------------------------------------------------
// helpers
// ---------------------------------------------------------------------------
template<int CTRL>
__device__ __forceinline__ float dpp_rot(float x) {
    return __int_as_float(__builtin_amdgcn_update_dpp(
        0, __float_as_int(x), CTRL, 0xF, 0xF, true));
}
// sum across each 16-lane row via rotational Hillis-Steele (pure VALU DPP)
__device__ __forceinline__ float reduce16(float x) {
    x += dpp_rot<0x121>(x);   // row_ror:1
    x += dpp_rot<0x122>(x);   // row_ror:2
    x += dpp_rot<0x124>(x);   // row_ror:4
    x += dpp_rot<0x128>(x);   // row_ror:8
    return x;
}
__device__ __forceinline__ unsigned short f2bf(float f) {
    unsigned u = __float_as_uint(f);
    unsigned r = (u + 0x7FFFu + ((u >> 16) & 1u)) >> 16;   // RNE
    return (unsigned short)r;
}
__device__ __forceinline__ float bf2f(unsigned short u) {
    return __uint_as_float((unsigned)u << 16);
}
// fp16 weight from packed CSR record
__device__ __forceinline__ float rec_w(unsigned rec) {
    return __half2float(__ushort_as_half((unsigned short)(rec & 0xffffu)));
}

// ---------------------------------------------------------------------------
// K1: CSR build into padded 4B slots: rec = (src<<16) | fp16(weight).
// counts pre-zeroed by memset.  One atomic + one 4B store per edge.
// ---------------------------------------------------------------------------
__global__ void scatter_all(const int* __restrict__ edges, const float* __restrict__ ew,
                            int* counts, unsigned* __restrict__ csr, int nE) {
    int e = blockIdx.x * blockDim.x + threadIdx.x;
    if (e < nE) {
        int dst = edges[nE + e];           // edges[1][e]
        int src = edges[e];
        float w = ew[e];
        int p = atomicAdd(&counts[dst], 1);
        unsigned rec = ((unsigned)src << 16)
                     | (unsigned)__half_as_ushort(__float2half(w));
        csr[(dst << 6) + p] = rec;
    }
}

// ---------------------------------------------------------------------------
// Shared f32 GEMM tile helpers (XOR-swizzled transposed A store).
// ---------------------------------------------------------------------------
__device__ __forceinline__ void tile_load_A(float (*As)[68], const float* __restrict__ A,
                                            int row0, int n, int tid) {
    int c4 = (tid & 15) * 4;
    int sw = (tid & 7) << 2;
    #pragma unroll
    for (int it = 0; it < 4; ++it) {
        int r = (tid >> 4) + it * 16;
        float4 val = make_float4(0.f, 0.f, 0.f, 0.f);
        if (row0 + r < n)
            val = *reinterpret_cast<const float4*>(A + (size_t)(row0 + r) * DIM + c4);
        int rs = r ^ sw;
        As[c4 + 0][rs] = val.x;
        As[c4 + 1][rs] = val.y;
        As[c4 + 2][rs] = val.z;
        As[c4 + 3][rs] = val.w;
    }
}

__device__ __forceinline__ void tile_mm(const float (*As)[68], const float (*Bs)[68],
                                        float acc[4][4], int r0, int c0) {
    #pragma unroll 8
    for (int kk = 0; kk < 64; ++kk) {
        int sw = ((kk >> 2) & 7) << 2;
        float4 av = *reinterpret_cast<const float4*>(&As[kk][r0 ^ sw]);
        float4 bv = *reinterpret_cast<const float4*>(&Bs[kk][c0]);
        float a_[4] = {av.x, av.y, av.z, av.w};
        float b_[4] = {bv.x, bv.y, bv.z, bv.w};
        #pragma unroll
        for (int i = 0; i < 4; ++i)
            #pragma unroll
            for (int j = 0; j < 4; ++j)
                acc[i][j] += a_[i] * b_[j];
    }
}

// ---------------------------------------------------------------------------
// K2: xws = dinv[row] * (f_mole @ gcn_w) in bf16.  deg/dinv computed in-kernel
// from the padded CSR (threads 0..63, one row each, result staged in LDS).
// ---------------------------------------------------------------------------
__global__ __launch_bounds__(256) void gemm_xw(const float* __restrict__ A,
                                               const float* __restrict__ W,
                                               const int* __restrict__ counts,
                                               const unsigned* __restrict__ csr,
                                               float* __restrict__ dinv,
                                               unsigned short* __restrict__ out,
                                               int n) {
    __shared__ float As[64][68];
    __shared__ float Bs[64][68];
    __shared__ float dloc[64];
    int row0 = blockIdx.x * 64;
    int tid = threadIdx.x;

    if (tid < 64) {
        int r = row0 + tid;
        if (r < n) {
            int c = counts[r];
            const unsigned* p = csr + ((size_t)r << 6);
            float s = 0.f;
            for (int j = 0; j < c; ++j) s += rec_w(p[j]);
            float d = rsqrtf(s + 1.0f);    // +1 = self-loop weight
            dinv[r] = d;
            dloc[tid] = d;
        }
    }

    tile_load_A(As, A, row0, n, tid);
    #pragma unroll
    for (int it = 0; it < 4; ++it) {
        int r  = (tid >> 4) + it * 16;
        int c4 = (tid & 15) * 4;
        *reinterpret_cast<float4*>(&Bs[r][c4]) =
            *reinterpret_cast<const float4*>(W + (size_t)r * DIM + c4);
    }
    __syncthreads();
    int r0 = (tid >> 4) * 4;
    int c0 = (tid & 15) * 4;
    float acc[4][4] = {};
    tile_mm(As, Bs, acc, r0, c0);
    #pragma unroll
    for (int i = 0; i < 4; ++i) {
        int r = row0 + r0 + i;
        if (r >= n) continue;
        float d = dloc[r0 + i];
        ushort4 u;
        u.x = f2bf(d * acc[i][0]); u.y = f2bf(d * acc[i][1]);
        u.z = f2bf(d * acc[i][2]); u.w = f2bf(d * acc[i][3]);
        *reinterpret_cast<ushort4*>(out + (size_t)r * DIM + c0) = u;
    }
}

// ---------------------------------------------------------------------------
// K3: GCN aggregation.  4B CSR records; output f_gcn bf16.
// ---------------------------------------------------------------------------
__global__ __launch_bounds__(256) void gcn_agg(const unsigned short* __restrict__ xws,
                                               const int* __restrict__ counts,
                                               const unsigned* __restrict__ csr,
                                               const float* __restrict__ dinv,
                                               const float* __restrict__ gcn_b,
                                               unsigned short* __restrict__ f_gcnh, int n) {
    int wave = threadIdx.x >> 6;
    int lane = threadIdx.x & 63;
    int i = blockIdx.x * 4 + wave;
    if (i >= n) return;
    int eo = lane >> 4;
    int cg = lane & 15;

    float4 acc = make_float4(0.f, 0.f, 0.f, 0.f);
    int e0 = i << 6;
    int e1 = e0 + counts[i];
    int eb = e0;
    for (; eb + 16 <= e1; eb += 16) {
        unsigned p[4];
        #pragma unroll
        for (int j = 0; j < 4; ++j) p[j] = csr[eb + 4 * j + eo];
        ushort4 x[4];
        #pragma unroll
        for (int j = 0; j < 4; ++j)
            x[j] = *reinterpret_cast<const ushort4*>(xws + (size_t)(p[j] >> 16) * DIM + cg * 4);
        #pragma unroll
        for (int j = 0; j < 4; ++j) {
            float c = rec_w(p[j]);
            acc.x += c * bf2f(x[j].x); acc.y += c * bf2f(x[j].y);
            acc.z += c * bf2f(x[j].z); acc.w += c * bf2f(x[j].w);
        }
    }
    for (int e = eb + eo; e < e1; e += 4) {
        unsigned p = csr[e];
        float c = rec_w(p);
        ushort4 x4 = *reinterpret_cast<const ushort4*>(xws + (size_t)(p >> 16) * DIM + cg * 4);
        acc.x += c * bf2f(x4.x); acc.y += c * bf2f(x4.y);
        acc.z += c * bf2f(x4.z); acc.w += c * bf2f(x4.w);
    }
    acc.x += __shfl_xor(acc.x, 16, 64); acc.x += __shfl_xor(acc.x, 32, 64);
    acc.y += __shfl_xor(acc.y, 16, 64); acc.y += __shfl_xor(acc.y, 32, 64);
    acc.z += __shfl_xor(acc.z, 16, 64); acc.z += __shfl_xor(acc.z, 32, 64);
    acc.w += __shfl_xor(acc.w, 16, 64); acc.w += __shfl_xor(acc.w, 32, 64);

    float di = dinv[i];
    ushort4 xs = *reinterpret_cast<const ushort4*>(xws + (size_t)i * DIM + cg * 4);
    const float* b = gcn_b + cg * 4;
    if (eo == 0) {
        ushort4 u;
        u.x = f2bf(fmaxf(di * (acc.x + bf2f(xs.x)) + b[0], 0.f));
        u.y = f2bf(fmaxf(di * (acc.y + bf2f(xs.y)) + b[1], 0.f));
        u.z = f2bf(fmaxf(di * (acc.z + bf2f(xs.z)) + b[2], 0.f));
        u.w = f2bf(fmaxf(di * (acc.w + bf2f(xs.w)) + b[3], 0.f));
        *reinterpret_cast<ushort4*>(f_gcnh + (size_t)i * DIM + cg * 4) = u;
    }
}

// ---------------------------------------------------------------------------
// K4: q/k/v/skip projections via MFMA (bf16 inputs, f32 accumulate).
// 2D grid = (row_tiles, 13): ty 0..3 q (bf16 out, x0.125), 4..7 k, 8..11 v
// (k,v -> interleaved kv buffer), ty 12 skip (f32 out).
// ---------------------------------------------------------------------------
__global__ __launch_bounds__(256) void qkv_mfma(const unsigned short* __restrict__ Ah,
        const float* __restrict__ wq, const float* __restrict__ bq,
        const float* __restrict__ wk, const float* __restrict__ bk,
        const float* __restrict__ wv, const float* __restrict__ bv,
        const float* __restrict__ wsk, const float* __restrict__ bsk,
        unsigned short* __restrict__ qo, unsigned short* __restrict__ kvb,
        float* __restrict__ xrb, int n) {
    int ty = blockIdx.y;            // 0..12
    const float* W; const float* bias; float scale = 1.0f;
    int ncw, mode;                  // 0=q, 1=k, 2=v, 3=skip
    int col0 = (ty & 3) * 64;
    if (ty < 4)       { W = wq;  bias = bq;  ncw = HD;  mode = 0; scale = 0.125f; }
    else if (ty < 8)  { W = wk;  bias = bk;  ncw = HD;  mode = 1; }
    else if (ty < 12) { W = wv;  bias = bv;  ncw = HD;  mode = 2; }
    else              { W = wsk; bias = bsk; ncw = DIM; mode = 3; col0 = 0; }

    int row0 = blockIdx.x * 64;
    int wid  = threadIdx.x >> 6;
    int lane = threadIdx.x & 63;
    int hm = wid >> 1, hn = wid & 1;
    int lrow = lane & 15;
    int lk8  = (lane >> 4) * 8;

    // A fragments: 16B bf16 loads
    bf16x8 afr[2][2];   // [ks][fm]
    #pragma unroll
    for (int ks = 0; ks < 2; ++ks)
        #pragma unroll
        for (int fm = 0; fm < 2; ++fm) {
            int r = row0 + hm * 32 + fm * 16 + lrow;
            bf16x8 v8;
            if (r < n) {
                v8 = *reinterpret_cast<const bf16x8*>(Ah + (size_t)r * DIM + ks * 32 + lk8);
            } else {
                #pragma unroll
                for (int j = 0; j < 8; ++j) v8[j] = 0;
            }
            afr[ks][fm] = v8;
        }

    // B fragments: strided f32 -> bf16
    bf16x8 bfr[2][2];   // [ks][fn]
    #pragma unroll
    for (int ks = 0; ks < 2; ++ks)
        #pragma unroll
        for (int fn = 0; fn < 2; ++fn) {
            int c = col0 + hn * 32 + fn * 16 + lrow;
            const float* wp = W + (size_t)(ks * 32 + lk8) * ncw + c;
            bf16x8 v8;
            #pragma unroll
            for (int j = 0; j < 8; ++j)
                v8[j] = (short)f2bf(wp[(size_t)j * ncw]);
            bfr[ks][fn] = v8;
        }

    f32x4 zz = {0.f, 0.f, 0.f, 0.f};
    f32x4 acc[2][2] = {{zz, zz}, {zz, zz}};
    #pragma unroll
    for (int ks = 0; ks < 2; ++ks)
        #pragma unroll
        for (int fm = 0; fm < 2; ++fm)
            #pragma unroll
            for (int fn = 0; fn < 2; ++fn)
                acc[fm][fn] = __builtin_amdgcn_mfma_f32_16x16x32_bf16(
                    afr[ks][fm], bfr[ks][fn], acc[fm][fn], 0, 0, 0);

    int drow = (lane >> 4) * 4;
    int dcol = lane & 15;
    #pragma unroll
    for (int fm = 0; fm < 2; ++fm)
        #pragma unroll
        for (int fn = 0; fn < 2; ++fn) {
            int col = col0 + hn * 32 + fn * 16 + dcol;
            float bcol = bias[col];
            #pragma unroll
            for (int r = 0; r < 4; ++r) {
                int row = row0 + hm * 32 + fm * 16 + drow + r;
                if (row >= n) continue;
                float val = (acc[fm][fn][r] + bcol) * scale;
                if (mode == 0) {
                    qo[(size_t)row * HD + col] = f2bf(val);
                } else if (mode == 3) {
                    xrb[(size_t)row * DIM + col] = val;
                } else {
                    int h = col >> 6, c6 = col & 63;
                    kvb[(size_t)row * 512 + h * 128 + (c6 >> 2) * 8 + (c6 & 3)
                        + (mode == 2 ? 4 : 0)] = f2bf(val);
                }
            }
        }
}

// ---------------------------------------------------------------------------
// K5: fused attention + beta gate.  One wave per node.
// lane = (head = lane>>4, 4-chan group = lane&15).  kv interleaved bf16
// (one dwordx4 gather per edge per lane); q bf16, pre-scaled by 0.125.
// 8-edge unroll.  Logits small -> no max-tracking.
// ---------------------------------------------------------------------------
__global__ __launch_bounds__(256) void attn_fused(const unsigned short* __restrict__ q,
                                                  const unsigned short* __restrict__ kvb,
                                                  const float* __restrict__ x_r,
                                                  const int* __restrict__ counts,
                                                  const unsigned* __restrict__ csr,
                                                  const float* __restrict__ wbeta,
                                                  float* __restrict__ f_tf, int n) {
    int wave = threadIdx.x >> 6;
    int lane = threadIdx.x & 63;
    int i = blockIdx.x * 4 + wave;
    if (i >= n) return;
    int h  = lane >> 4;
    int cg = lane & 15;
    int kvoff = h * 128 + cg * 8;

    ushort4 qv = *reinterpret_cast<const ushort4*>(q + (size_t)i * HD + h * DIM + cg * 4);
    float4 q4;
    q4.x = bf2f(qv.x); q4.y = bf2f(qv.y); q4.z = bf2f(qv.z); q4.w = bf2f(qv.w);
    float z = 0.f;
    float4 a = make_float4(0.f, 0.f, 0.f, 0.f);

    int e0 = i << 6;
    int cnt = counts[i];
    int e1 = e0 + cnt;
    int e = e0;
    for (; e + 8 <= e1; e += 8) {
        int s[8];
        #pragma unroll
        for (int j = 0; j < 8; ++j) s[j] = (int)(csr[e + j] >> 16);
        u16x8 kv[8];
        #pragma unroll
        for (int j = 0; j < 8; ++j)
            kv[j] = *reinterpret_cast<const u16x8*>(kvb + (size_t)s[j] * 512 + kvoff);
        float pl[8];
        #pragma unroll
        for (int j = 0; j < 8; ++j)
            pl[j] = q4.x * bf2f(kv[j][0]) + q4.y * bf2f(kv[j][1])
                  + q4.z * bf2f(kv[j][2]) + q4.w * bf2f(kv[j][3]);
        #pragma unroll
        for (int j = 0; j < 8; ++j) pl[j] = reduce16(pl[j]);
        #pragma unroll
        for (int j = 0; j < 8; ++j) {
            float ez = __expf(pl[j]);
            z += ez;
            a.x += ez * bf2f(kv[j][4]); a.y += ez * bf2f(kv[j][5]);
            a.z += ez * bf2f(kv[j][6]); a.w += ez * bf2f(kv[j][7]);
        }
    }
    for (; e + 4 <= e1; e += 4) {
        int s[4];
        #pragma unroll
        for (int j = 0; j < 4; ++j) s[j] = (int)(csr[e + j] >> 16);
        u16x8 kv[4];
        #pragma unroll
        for (int j = 0; j < 4; ++j)
            kv[j] = *reinterpret_cast<const u16x8*>(kvb + (size_t)s[j] * 512 + kvoff);
        #pragma unroll
        for (int j = 0; j < 4; ++j) {
            float p = q4.x * bf2f(kv[j][0]) + q4.y * bf2f(kv[j][1])
                    + q4.z * bf2f(kv[j][2]) + q4.w * bf2f(kv[j][3]);
            p = reduce16(p);
            float ez = __expf(p);
            z += ez;
            a.x += ez * bf2f(kv[j][4]); a.y += ez * bf2f(kv[j][5]);
            a.z += ez * bf2f(kv[j][6]); a.w += ez * bf2f(kv[j][7]);
        }
    }
    for (; e < e1; ++e) {
        int s = (int)(csr[e] >> 16);
        u16x8 kv = *reinterpret_cast<const u16x8*>(kvb + (size_t)s * 512 + kvoff);
        float p = q4.x * bf2f(kv[0]) + q4.y * bf2f(kv[1])
                + q4.z * bf2f(kv[2]) + q4.w * bf2f(kv[3]);
        p = reduce16(p);
        float ez = __expf(p);
        z += ez;
        a.x += ez * bf2f(kv[4]); a.y += ez * bf2f(kv[5]);
        a.z += ez * bf2f(kv[6]); a.w += ez * bf2f(kv[7]);
    }

    float inv = (cnt > 0) ? 1.0f / z : 0.f;
    float4 o;
    o.x = a.x * inv; o.y = a.y * inv; o.z = a.z * inv; o.w = a.w * inv;
    o.x += __shfl_xor(o.x, 16, 64); o.x += __shfl_xor(o.x, 32, 64);
    o.y += __shfl_xor(o.y, 16, 64); o.y += __shfl_xor(o.y, 32, 64);
    o.z += __shfl_xor(o.z, 16, 64); o.z += __shfl_xor(o.z, 32, 64);
    o.w += __shfl_xor(o.w, 16, 64); o.w += __shfl_xor(o.w, 32, 64);
    o.x *= 0.25f; o.y *= 0.25f; o.z *= 0.25f; o.w *= 0.25f;

    float4 xr4 = *reinterpret_cast<const float4*>(x_r + (size_t)i * DIM + cg * 4);
    const float* w1 = wbeta + cg * 4;
    const float* w2 = wbeta + 64 + cg * 4;
    const float* w3 = wbeta + 128 + cg * 4;
    float t = o.x * w1[0] + o.y * w1[1] + o.z * w1[2] + o.w * w1[3]
            + xr4.x * w2[0] + xr4.y * w2[1] + xr4.z * w2[2] + xr4.w * w2[3]
            + (o.x - xr4.x) * w3[0] + (o.y - xr4.y) * w3[1]
            + (o.z - xr4.z) * w3[2] + (o.w - xr4.w) * w3[3];
    t = reduce16(t);
    float beta = 1.0f / (1.0f + __expf(-t));
    float4 r;
    r.x = fmaxf(beta * xr4.x + (1.0f - beta) * o.x, 0.f);
    r.y = fmaxf(beta * xr4.y + (1.0f - beta) * o.y, 0.f);
    r.z = fmaxf(beta * xr4.z + (1.0f - beta) * o.z, 0.f);
    r.w = fmaxf(beta * xr4.w + (1.0f - beta) * o.w, 0.f);
    if (h == 0)
        *reinterpret_cast<float4*>(f_tf + (size_t)i * DIM + cg * 4) = r;
}

// ---------------------------------------------------------------------------
// K6: conv projection, LDS-staged read-once tile.
// block = 64 nodes; stage f_tf tile (64x64, padded) in LDS; thread (o-group,
// node) computes 16 outputs; stores coalesced along n.
// ---------------------------------------------------------------------------
__global__ __launch_bounds__(256) void conv_out_k(const float* __restrict__ f_tf,
                                                  const float* __restrict__ conv_w,
                                                  const float* __restrict__ conv_b,
                                                  float* __restrict__ out, int n) {
    __shared__ float ft[64][65];
    int n0 = blockIdx.x * 64;
    int tid = threadIdx.x;
    int nd = tid >> 2, c16 = (tid & 3) * 16;
    if (n0 + nd < n) {
        #pragma unroll
        for (int j = 0; j < 4; ++j) {
            float4 v = *reinterpret_cast<const float4*>(
                f_tf + (size_t)(n0 + nd) * DIM + c16 + j * 4);
            ft[nd][c16 + j * 4 + 0] = v.x;
            ft[nd][c16 + j * 4 + 1] = v.y;
            ft[nd][c16 + j * 4 + 2] = v.z;
            ft[nd][c16 + j * 4 + 3] = v.w;
        }
    }
    __syncthreads();
    int nl = tid & 63;
    int og = tid >> 6;                // 0..3
    int nn = n0 + nl;
    if (nn >= n) return;
    #pragma unroll 1
    for (int oo = 0; oo < 16; ++oo) {
        int o = og * 16 + oo;
        const float* wr = conv_w + (size_t)o * DIM;
        float acc = conv_b[o];
        #pragma unroll
        for (int k = 0; k < 64; ++k) acc += ft[nl][k] * wr[k];
        out[(size_t)o * n + nn] = acc;
    }
}

// ---------------------------------------------------------------------------
// launch
// ---------------------------------------------------------------------------
extern "C" void kernel_launch(void* const* d_in, const int* in_sizes, int n_in,
                              void* d_out, int out_size, void* d_ws, size_t ws_size,
                              hipStream_t stream) {
    const float* f_mole = (const float*)d_in[0];
    const float* edge_w = (const float*)d_in[1];
    const float* gcn_w  = (const float*)d_in[2];
    const float* gcn_b  = (const float*)d_in[3];
    const float* wq     = (const float*)d_in[4];
    const float* bq     = (const float*)d_in[5];
    const float* wk     = (const float*)d_in[6];
    const float* bk     = (const float*)d_in[7];
    const float* wv     = (const float*)d_in[8];
    const float* bv     = (const float*)d_in[9];
    const float* wskip  = (const float*)d_in[10];
    const float* bskip  = (const float*)d_in[11];
    const float* wbeta  = (const float*)d_in[12];
    const float* conv_w = (const float*)d_in[13];
    const float* conv_b = (const float*)d_in[14];
    const int*   edges  = (const int*)d_in[15];

    int N = in_sizes[0] / DIM;
    int E = in_sizes[1];

    float* ws = (float*)d_ws;
    size_t o = 0;
    int*      counts = (int*)(ws + o);      o += N;      // must stay first (memset)
    float*    dinv   = ws + o;              o += N;
    unsigned* csr    = (unsigned*)(ws + o); o += (size_t)N * CAP;
    unsigned short* xws    = (unsigned short*)(ws + o); o += (size_t)N * DIM / 2;
    unsigned short* f_gcnh = (unsigned short*)(ws + o); o += (size_t)N * DIM / 2;
    unsigned short* qb     = (unsigned short*)(ws + o); o += (size_t)N * HD / 2;
    unsigned short* kvb    = (unsigned short*)(ws + o); o += (size_t)N * 512 / 2;
    float* xrb = ws + o;                    o += (size_t)N * DIM;
    float* ftf = ws + o;                    o += (size_t)N * DIM;

    int ebl = (E + 255) / 256;
    int gbl = (N + 63) / 64;

    hipMemsetAsync(d_ws, 0, (size_t)N * sizeof(int), stream);
    scatter_all<<<ebl, 256, 0, stream>>>(edges, edge_w, counts, csr, E);

    gemm_xw<<<gbl, 256, 0, stream>>>(f_mole, gcn_w, counts, csr, dinv, xws, N);
    gcn_agg<<<(N + 3) / 4, 256, 0, stream>>>(xws, counts, csr, dinv, gcn_b, f_gcnh, N);

    qkv_mfma<<<dim3(gbl, 13), 256, 0, stream>>>(f_gcnh, wq, bq, wk, bk, wv, bv,
                                                wskip, bskip, qb, kvb, xrb, N);

    attn_fused<<<(N + 3) / 4, 256, 0, stream>>>(qb, kvb, xrb, counts, csr, wbeta, ftf, N);
    conv_out_k<<<gbl, 256, 0, stream>>>(ftf, conv_w, conv_b, (float*)d_out, N);
}